// Round 5
// baseline (393.955 us; speedup 1.0000x reference)
//
#include <hip/hip_runtime.h>
#include <cstdint>

#define V_ 25
#define T_ 128
#define VT_ 3200
#define NVTF_ 204800.0f

typedef unsigned short ushort_t;
typedef __attribute__((ext_vector_type(8))) short s16x8;
typedef __attribute__((ext_vector_type(4))) float f32x4;

__device__ __forceinline__ ushort_t f2bf(float f) {
    union { float f; unsigned u; } v; v.f = f;
    unsigned r = v.u + 0x7FFFu + ((v.u >> 16) & 1u);
    return (ushort_t)(r >> 16);
}
__device__ __forceinline__ float bf2f(ushort_t h) {
    union { unsigned u; float f; } v; v.u = ((unsigned)h) << 16;
    return v.f;
}
__device__ __forceinline__ void gload16(const void* g, void* l) {
    __builtin_amdgcn_global_load_lds((const __attribute__((address_space(1))) void*)g,
                                     (__attribute__((address_space(3))) void*)l, 16, 0, 0);
}

// ---------------- k_a: a1/a2 = wg @ x (bf16 out) + xb bf16 [m][64] ----------------
__global__ __launch_bounds__(128) void k_a(const float* __restrict__ x,
        const float* __restrict__ wg1, const float* __restrict__ wg2,
        ushort_t* __restrict__ a1, ushort_t* __restrict__ a2,
        ushort_t* __restrict__ xb) {
    int b = blockIdx.x; int n = b / V_; int v = b % V_;
    int t = threadIdx.x;
    __shared__ float w1s[1024], w2s[1024];
    for (int i = threadIdx.x; i < 1024; i += 128) { w1s[i] = wg1[i]; w2s[i] = wg2[i]; }
    __syncthreads();
    float s1[16], s2[16];
    #pragma unroll
    for (int o = 0; o < 16; o++) { s1[o] = 0.f; s2[o] = 0.f; }
    s16x8 xs[8];
    const float* xp = x + (size_t)n * 204800 + v * T_ + t;
    #pragma unroll
    for (int c = 0; c < 64; c++) {
        float xv = xp[(size_t)c * VT_];
        xs[c >> 3][c & 7] = (short)f2bf(xv);
        #pragma unroll
        for (int o = 0; o < 16; o++) {
            s1[o] = fmaf(w1s[o*64+c], xv, s1[o]);
            s2[o] = fmaf(w2s[o*64+c], xv, s2[o]);
        }
    }
    size_t abase = (size_t)n * 51200 + v * T_ + t;
    #pragma unroll
    for (int o = 0; o < 16; o++) {
        a1[abase + (size_t)o * VT_] = f2bf(s1[o]);
        a2[abase + (size_t)o * VT_] = f2bf(s2[o]);
    }
    ushort_t* cp = xb + (size_t)(n * VT_ + v * T_ + t) * 64;
    #pragma unroll
    for (int ch = 0; ch < 8; ch++) *(s16x8*)(cp + ch * 8) = xs[ch];
}

// ---------------- k_g: g = softmax(a1^T a2), fp32 (d_out) + bf16 copy ----------------
__global__ __launch_bounds__(256) void k_g(const ushort_t* __restrict__ a1,
        const ushort_t* __restrict__ a2, float* __restrict__ g,
        ushort_t* __restrict__ gb) {
    int n = blockIdx.x >> 3; int t0 = (blockIdx.x & 7) * 16;
    __shared__ float A1s[6400], A2s[6400]; // [o][v][tt]
    for (int i = threadIdx.x; i < 6400; i += 256) {
        int o = i / 400; int r = i % 400; int v = r >> 4; int tt = r & 15;
        size_t ga = (size_t)n * 51200 + (size_t)o * VT_ + v * T_ + t0 + tt;
        A1s[i] = bf2f(a1[ga]);
        A2s[i] = bf2f(a2[ga]);
    }
    __syncthreads();
    for (int r = threadIdx.x; r < 400; r += 256) {
        int v = r >> 4; int tt = r & 15;
        float a1r[16];
        #pragma unroll
        for (int o = 0; o < 16; o++) a1r[o] = A1s[o*400 + v*16 + tt];
        float gr[25];
        float mx = -1e30f;
        for (int u = 0; u < 25; u++) {
            float s = 0.f;
            #pragma unroll
            for (int o = 0; o < 16; o++) s = fmaf(a1r[o], A2s[o*400 + u*16 + tt], s);
            gr[u] = s; mx = fmaxf(mx, s);
        }
        float sum = 0.f;
        for (int u = 0; u < 25; u++) { gr[u] = __expf(gr[u] - mx); sum += gr[u]; }
        float inv = 1.f / sum;
        size_t goff = ((size_t)(n * T_ + t0 + tt) * V_ + v) * V_;
        float* gp = g + goff;
        ushort_t* gbp = gb + goff;
        for (int u = 0; u < 25; u++) {
            float val = gr[u] * inv;
            gp[u] = val;
            gbp[u] = f2bf(val);
        }
    }
}

// ---------------- all weight concats -> bf16 (one launch) ----------------
__global__ void k_wcat(const float* __restrict__ w11, const float* __restrict__ w12,
        const float* __restrict__ w21, const float* __restrict__ w22,
        const float* __restrict__ w31, const float* __restrict__ w32,
        ushort_t* __restrict__ Wc) {
    int i = blockIdx.x * 256 + threadIdx.x; // 352*256 = 90112 exact
    float v;
    if (i < 8192) {
        int o = i >> 7, k = i & 127;
        v = (k < 64) ? w11[o * 64 + k] : w12[o * 64 + k - 64];
    } else if (i < 24576) {
        int j = i - 8192; int o = j >> 7, k = j & 127;
        v = (k < 64) ? w21[o * 64 + k] : w22[o * 64 + k - 64];
    } else {
        int j = i - 24576; int o = j >> 8, k = j & 255;
        v = (k < 128) ? w31[o * 128 + k] : w32[o * 128 + k - 128];
    }
    Wc[i] = f2bf(v);
}

// ---------------- k_bnmp: [BN+ReLU on input] + message passing ----------------
// mp[n][m][c] = sum_u g[n,t,v,u] * bn(yin[n][u*T+t][c])
template<int C, bool BN>
__global__ __launch_bounds__(256) void k_bnmp(const ushort_t* __restrict__ yin,
        const ushort_t* __restrict__ gb, const float* __restrict__ bns,
        const float* __restrict__ bnb, ushort_t* __restrict__ mp) {
    const int NC8 = C / 8;
    const int ITEMS = 25 * 8 * NC8;
    int n = blockIdx.y, t0 = blockIdx.x * 8;
    __shared__ float Gs[5200];          // [tt][v][u] pad 26
    __shared__ ushort_t Ys[25 * 8 * C]; // [u][tt][c]
    const ushort_t* gsrc = gb + ((size_t)(n * T_ + t0)) * 625;
    for (int i = threadIdx.x; i < 5000; i += 256) {
        int tt = i / 625, r = i % 625, v = r / 25, u = r % 25;
        Gs[(tt * 25 + v) * 26 + u] = bf2f(gsrc[i]);
    }
    for (int i = threadIdx.x; i < ITEMS; i += 256) {
        int u = i / (8 * NC8);
        int rem = i % (8 * NC8);
        int tt = rem / NC8, ch = rem % NC8;
        size_t srow = (size_t)n * VT_ + u * T_ + t0 + tt;
        s16x8 vv = *(const s16x8*)(yin + srow * C + ch * 8);
        s16x8 pk;
        if (BN) {
            #pragma unroll
            for (int j = 0; j < 8; j++) {
                int o = ch * 8 + j;
                float f = fmaf(bf2f((ushort_t)vv[j]), bns[o], bnb[o]);
                pk[j] = (short)f2bf(fmaxf(f, 0.f));
            }
        } else pk = vv;
        *(s16x8*)(&Ys[(u * 8 + tt) * C + ch * 8]) = pk;
    }
    __syncthreads();
    for (int i = threadIdx.x; i < ITEMS; i += 256) {
        int v = i / (8 * NC8);
        int rem = i % (8 * NC8);
        int tt = rem / NC8, ch = rem % NC8;
        const float* gw = &Gs[(tt * 25 + v) * 26];
        float acc[8] = {0.f,0.f,0.f,0.f,0.f,0.f,0.f,0.f};
        #pragma unroll
        for (int u = 0; u < 25; u++) {
            float wv = gw[u];
            s16x8 xv = *(const s16x8*)(&Ys[(u * 8 + tt) * C + ch * 8]);
            #pragma unroll
            for (int j = 0; j < 8; j++) acc[j] = fmaf(wv, bf2f((ushort_t)xv[j]), acc[j]);
        }
        s16x8 pk;
        #pragma unroll
        for (int j = 0; j < 8; j++) pk[j] = (short)f2bf(acc[j]);
        *(s16x8*)(mp + ((size_t)n * VT_ + v * T_ + t0 + tt) * C + ch * 8) = pk;
    }
}

// ---------------- MFMA GEMM: y[o][m] = sum_k Wc[o][k] * B[m][k] ----------------
// B-halves from two sources: bsrc1 (k<C), bsrc2 (k>=C, +BN+ReLU if BNB), stride C.
// Sibling-XCD swizzle: the NO o-blocks of one (m,n) tile share L%8 (same XCD).
// TOUT=0: bf16 [n][m][O]; TOUT=2: bf16 [n][O][m]
template<int TOUT, bool BNB, int NO>
__global__ __launch_bounds__(256) void k_gemm(const ushort_t* __restrict__ Wc,
        const ushort_t* __restrict__ bsrc1, const ushort_t* __restrict__ bsrc2,
        const float* __restrict__ bns, const float* __restrict__ bnb,
        ushort_t* __restrict__ yt,
        float* __restrict__ psum, float* __restrict__ psq, int K2, int O) {
    __shared__ __align__(16) char smem[24576]; // A: 8KB @0, B: 16KB @8192
    int L = blockIdx.x;
    int low = L & 7, q = L >> 3;
    int s = q % NO, h = q / NO;
    int g = h * 8 + low;              // 0..1599
    int mb = g % 25, n = g / 25;
    int m0 = mb * 128, o0 = s * 64;
    int C = K2 >> 1;
    int tid = threadIdx.x, w = tid >> 6, lane = tid & 63;
    int wo = w >> 1, wm = w & 1, l15 = lane & 15, g4 = lane >> 4;
    f32x4 acc[2][4] = {};
    for (int k0 = 0; k0 < K2; k0 += 64) {
        #pragma unroll
        for (int i = 0; i < 2; i++) {  // A: 64 rows x 8 chunks (swizzled), async
            int it = i * 256 + w * 64 + lane;
            int r = it >> 3, csw = it & 7, c = csw ^ (r & 7);
            gload16(Wc + (size_t)(o0 + r) * K2 + k0 + c * 8,
                    smem + (i * 256 + w * 64) * 16);
        }
        {   // B: 128 rows x 8 chunks, reg-staged (+BN on 2nd half)
            const ushort_t* bsrc = (k0 < C) ? bsrc1 : bsrc2;
            int koff = (k0 < C) ? k0 : k0 - C;
            bool dobn = BNB && (k0 >= C);
            #pragma unroll
            for (int i = 0; i < 4; i++) {
                int item = i * 256 + tid;
                int r = item >> 3, cl = item & 7;
                int cg = cl ^ (r & 7);
                s16x8 vv = *(const s16x8*)(bsrc + ((size_t)n * VT_ + m0 + r) * C
                                           + koff + cg * 8);
                if (dobn) {
                    int ob = koff + cg * 8;
                    float sc[8], sh[8];
                    *(float4*)(sc)     = *(const float4*)(bns + ob);
                    *(float4*)(sc + 4) = *(const float4*)(bns + ob + 4);
                    *(float4*)(sh)     = *(const float4*)(bnb + ob);
                    *(float4*)(sh + 4) = *(const float4*)(bnb + ob + 4);
                    #pragma unroll
                    for (int j = 0; j < 8; j++) {
                        float f = fmaf(bf2f((ushort_t)vv[j]), sc[j], sh[j]);
                        vv[j] = (short)f2bf(fmaxf(f, 0.f));
                    }
                }
                *(s16x8*)(smem + 8192 + r * 128 + cl * 16) = vv;
            }
        }
        __syncthreads();
        #pragma unroll
        for (int kk = 0; kk < 2; kk++) {
            s16x8 aF[2], bF[4];
            #pragma unroll
            for (int oi = 0; oi < 2; oi++) {
                int row = wo * 32 + oi * 16 + l15;
                int ch = kk * 4 + g4;
                aF[oi] = *(const s16x8*)(smem + row * 128 + 16 * (ch ^ (row & 7)));
            }
            #pragma unroll
            for (int mi = 0; mi < 4; mi++) {
                int row = wm * 64 + mi * 16 + l15;
                int ch = kk * 4 + g4;
                bF[mi] = *(const s16x8*)(smem + 8192 + row * 128 + 16 * (ch ^ (row & 7)));
            }
            #pragma unroll
            for (int oi = 0; oi < 2; oi++)
                #pragma unroll
                for (int mi = 0; mi < 4; mi++)
                    acc[oi][mi] = __builtin_amdgcn_mfma_f32_16x16x32_bf16(
                        aF[oi], bF[mi], acc[oi][mi], 0, 0, 0);
        }
        __syncthreads();
    }
    // BN partial stats from fp32 accumulators
    #pragma unroll
    for (int oi = 0; oi < 2; oi++) {
        #pragma unroll
        for (int b = 0; b < 4; b++) {
            float ss = 0.f, qq = 0.f;
            #pragma unroll
            for (int mi = 0; mi < 4; mi++) {
                float v0 = acc[oi][mi][b];
                ss += v0; qq = fmaf(v0, v0, qq);
            }
            #pragma unroll
            for (int msk = 1; msk < 16; msk <<= 1) {
                ss += __shfl_xor(ss, msk, 16);
                qq += __shfl_xor(qq, msk, 16);
            }
            if (l15 == 0) {
                int o = o0 + wo * 32 + oi * 16 + 4 * g4 + b;
                int p = (n * 25 + mb) * 2 + wm;
                psum[(size_t)o * 3200 + p] = ss;
                psq [(size_t)o * 3200 + p] = qq;
            }
        }
    }
    if (TOUT == 0) {
        ushort_t* Lw = (ushort_t*)smem + w * 2176; // [64 m][34]
        #pragma unroll
        for (int oi = 0; oi < 2; oi++)
            #pragma unroll
            for (int mi = 0; mi < 4; mi++)
                #pragma unroll
                for (int b = 0; b < 4; b++)
                    Lw[(mi * 16 + l15) * 34 + oi * 16 + 4 * g4 + b] = f2bf(acc[oi][mi][b]);
        #pragma unroll
        for (int i = 0; i < 4; i++) {
            int item = i * 64 + lane;
            int ml = item >> 2, oc = item & 3;
            s16x8 pk;
            #pragma unroll
            for (int j = 0; j < 8; j++) pk[j] = (short)Lw[ml * 34 + oc * 8 + j];
            *(s16x8*)(yt + ((size_t)n * VT_ + m0 + wm * 64 + ml) * O
                         + o0 + wo * 32 + oc * 8) = pk;
        }
    } else {
        ushort_t* Lw = (ushort_t*)smem + w * 1152; // [16 o][72 m]
        #pragma unroll
        for (int oi = 0; oi < 2; oi++) {
            #pragma unroll
            for (int mi = 0; mi < 4; mi++)
                #pragma unroll
                for (int b = 0; b < 4; b++)
                    Lw[(4 * g4 + b) * 72 + mi * 16 + l15] = f2bf(acc[oi][mi][b]);
            #pragma unroll
            for (int it = 0; it < 2; it++) {
                int item = it * 64 + lane;
                int ol = item >> 3, mc = item & 7;
                s16x8 pk;
                #pragma unroll
                for (int j = 0; j < 8; j++) pk[j] = (short)Lw[ol * 72 + mc * 8 + j];
                *(s16x8*)(yt + ((size_t)n * O + o0 + wo * 32 + oi * 16 + ol) * VT_
                             + m0 + wm * 64 + mc * 8) = pk;
            }
        }
    }
}

// ---------------- finalize per-channel stats -> scale/shift arrays ----------------
__global__ __launch_bounds__(256) void k_stats(const float* __restrict__ psum,
        const float* __restrict__ psq, const float* __restrict__ gamma,
        const float* __restrict__ beta, float* __restrict__ bns,
        float* __restrict__ bnb) {
    int o = blockIdx.x;
    float s = 0.f, q = 0.f;
    for (int i = threadIdx.x; i < 3200; i += 256) {
        s += psum[(size_t)o*3200+i]; q += psq[(size_t)o*3200+i];
    }
    __shared__ float rs[256], rq[256];
    rs[threadIdx.x] = s; rq[threadIdx.x] = q;
    __syncthreads();
    for (int st = 128; st > 0; st >>= 1) {
        if (threadIdx.x < st) { rs[threadIdx.x] += rs[threadIdx.x+st]; rq[threadIdx.x] += rq[threadIdx.x+st]; }
        __syncthreads();
    }
    if (threadIdx.x == 0) {
        float mean = rs[0] / NVTF_;
        float var = rq[0] / NVTF_ - mean * mean;
        float scale = gamma[o] * rsqrtf(var + 1e-5f);
        bns[o] = scale;
        bnb[o] = beta[o] - mean * scale;
    }
}

// ---------------- final BN + ReLU: bf16 y3 [O][m] -> fp32 d_out ----------------
__global__ __launch_bounds__(256) void k_bnf(const ushort_t* __restrict__ y3,
        const float* __restrict__ bns, const float* __restrict__ bnb,
        float* __restrict__ xout) {
    const size_t total = 6553600; // 52.4M elems / 8
    size_t stride = (size_t)gridDim.x * 256;
    for (size_t i = (size_t)blockIdx.x * 256 + threadIdx.x; i < total; i += stride) {
        int o = (int)((i / 400) & 255);
        float sc = bns[o], sh = bnb[o];
        s16x8 v = ((const s16x8*)y3)[i];
        float* op = xout + i * 8;
        float4 f0, f1;
        f0.x = fmaxf(fmaf(bf2f((ushort_t)v[0]), sc, sh), 0.f);
        f0.y = fmaxf(fmaf(bf2f((ushort_t)v[1]), sc, sh), 0.f);
        f0.z = fmaxf(fmaf(bf2f((ushort_t)v[2]), sc, sh), 0.f);
        f0.w = fmaxf(fmaf(bf2f((ushort_t)v[3]), sc, sh), 0.f);
        f1.x = fmaxf(fmaf(bf2f((ushort_t)v[4]), sc, sh), 0.f);
        f1.y = fmaxf(fmaf(bf2f((ushort_t)v[5]), sc, sh), 0.f);
        f1.z = fmaxf(fmaf(bf2f((ushort_t)v[6]), sc, sh), 0.f);
        f1.w = fmaxf(fmaf(bf2f((ushort_t)v[7]), sc, sh), 0.f);
        *(float4*)op = f0;
        *(float4*)(op + 4) = f1;
    }
}

extern "C" void kernel_launch(void* const* d_in, const int* in_sizes, int n_in,
                              void* d_out, int out_size, void* d_ws, size_t ws_size,
                              hipStream_t stream) {
    const float* x   = (const float*)d_in[0];
    const float* wg1 = (const float*)d_in[1];
    const float* wg2 = (const float*)d_in[2];
    const float* w11 = (const float*)d_in[3];
    const float* w12 = (const float*)d_in[4];
    const float* ga1 = (const float*)d_in[5];
    const float* be1 = (const float*)d_in[6];
    const float* w21 = (const float*)d_in[7];
    const float* w22 = (const float*)d_in[8];
    const float* ga2 = (const float*)d_in[9];
    const float* be2 = (const float*)d_in[10];
    const float* w31 = (const float*)d_in[11];
    const float* w32 = (const float*)d_in[12];
    const float* ga3 = (const float*)d_in[13];
    const float* be3 = (const float*)d_in[14];

    float* xout = (float*)d_out;               // (64,256,25,128) fp32
    float* gout = xout + 52428800;             // (64,128,25,25) fp32

    float* ws = (float*)d_ws;
    // non-overlapping layout (floats)
    ushort_t* a1  = (ushort_t*)(ws + 0);          // 3,276,800 us
    ushort_t* a2  = (ushort_t*)(ws + 1638400);    // 3,276,800 us
    ushort_t* xb  = (ushort_t*)(ws + 3276800);    // 13,107,200 us [m][64]
    ushort_t* mp1 = (ushort_t*)(ws + 9830400);    // 13,107,200 us [m][64]
    ushort_t* y1  = (ushort_t*)(ws + 16384000);   // 13,107,200 us [m][64]
    ushort_t* mp2 = (ushort_t*)(ws + 22937600);   // 13,107,200 us [m][64]
    ushort_t* y2  = (ushort_t*)(ws + 29491200);   // 26,214,400 us [m][128]
    ushort_t* mp3 = (ushort_t*)(ws + 42598400);   // 26,214,400 us [m][128]
    ushort_t* y3  = (ushort_t*)(ws + 55705600);   // 52,428,800 us [O][m]
    ushort_t* gb  = (ushort_t*)(ws + 81920000);   // 5,120,000 us
    float* psum = ws + 84480000;                  // 819,200 fl
    float* psq  = ws + 85299200;                  // 819,200 fl
    ushort_t* Wc = (ushort_t*)(ws + 86118400);    // 90,112 us
    float* bns  = ws + 86163456;                  // 256 fl
    float* bnb  = ws + 86163712;                  // 256 fl
    ushort_t* Wc1 = Wc, *Wc2 = Wc + 8192, *Wc3 = Wc + 24576;

    k_a<<<1600, 128, 0, stream>>>(x, wg1, wg2, a1, a2, xb);
    k_g<<<512, 256, 0, stream>>>(a1, a2, gout, gb);
    k_wcat<<<352, 256, 0, stream>>>(w11, w12, w21, w22, w31, w32, Wc);

    // layer 1: C=64 -> O=64
    k_bnmp<64, false><<<dim3(16, 64), 256, 0, stream>>>(xb, gb, nullptr, nullptr, mp1);
    k_gemm<0, false, 1><<<1600, 256, 0, stream>>>(Wc1, mp1, xb, nullptr, nullptr,
                                                  y1, psum, psq, 128, 64);
    k_stats<<<64, 256, 0, stream>>>(psum, psq, ga1, be1, bns, bnb);

    // layer 2: C=64 -> O=128 (BN(y1) fused into MP and GEMM staging)
    k_bnmp<64, true><<<dim3(16, 64), 256, 0, stream>>>(y1, gb, bns, bnb, mp2);
    k_gemm<0, true, 2><<<3200, 256, 0, stream>>>(Wc2, mp2, y1, bns, bnb,
                                                 y2, psum, psq, 128, 128);
    k_stats<<<128, 256, 0, stream>>>(psum, psq, ga2, be2, bns, bnb);

    // layer 3: C=128 -> O=256
    k_bnmp<128, true><<<dim3(16, 64), 256, 0, stream>>>(y2, gb, bns, bnb, mp3);
    k_gemm<2, true, 4><<<6400, 256, 0, stream>>>(Wc3, mp3, y2, bns, bnb,
                                                 y3, psum, psq, 256, 256);
    k_stats<<<256, 256, 0, stream>>>(psum, psq, ga3, be3, bns, bnb);
    k_bnf<<<2048, 256, 0, stream>>>(y3, bns, bnb, xout);
}